// Round 1
// baseline (236.393 us; speedup 1.0000x reference)
//
#include <hip/hip_runtime.h>

typedef __attribute__((ext_vector_type(4))) float f32x4;
typedef __attribute__((ext_vector_type(8))) short short8;

#define DEV static __device__ __forceinline__

DEV unsigned short f2bf(float f) {
  union { float f; unsigned u; } x; x.f = f;
  unsigned r = x.u + 0x7fffu + ((x.u >> 16) & 1u);
  return (unsigned short)(r >> 16);
}

DEV f32x4 mfma16(short8 a, short8 b, f32x4 c) {
  return __builtin_amdgcn_mfma_f32_16x16x32_bf16(a, b, c, 0, 0, 0);
}

DEV void gload16(const void* g, void* l) {
  __builtin_amdgcn_global_load_lds(
      (const __attribute__((address_space(1))) void*)g,
      (__attribute__((address_space(3))) void*)l, 16, 0, 0);
}

// ---------------- fp32 -> bf16 elementwise ----------------
__global__ __launch_bounds__(256) void k_convert(const float* __restrict__ in,
                                                 unsigned short* __restrict__ out) {
  size_t i = (size_t)blockIdx.x * 256 + threadIdx.x;
  const f32x4* p = (const f32x4*)(in + i * 8);
  f32x4 a = p[0], b = p[1];
  short8 r;
  r[0] = f2bf(a[0]); r[1] = f2bf(a[1]); r[2] = f2bf(a[2]); r[3] = f2bf(a[3]);
  r[4] = f2bf(b[0]); r[5] = f2bf(b[1]); r[6] = f2bf(b[2]); r[7] = f2bf(b[3]);
  *(short8*)(out + i * 8) = r;
}

// ---------------- fp32 [R][C] -> bf16 [C][R] (weights) ----------------
__global__ __launch_bounds__(256) void k_transpose_f32_bf16(
    const float* __restrict__ in, unsigned short* __restrict__ out, int R, int C) {
  __shared__ unsigned short T[64 * 72];
  int r0 = blockIdx.y * 64, c0 = blockIdx.x * 64;
  int t = threadIdx.x;
  int rr = t >> 2, seg = t & 3;
  const float* p = in + (size_t)(r0 + rr) * C + c0 + seg * 16;
#pragma unroll
  for (int q = 0; q < 4; ++q) {
    f32x4 v = *(const f32x4*)(p + q * 4);
#pragma unroll
    for (int e = 0; e < 4; ++e) T[rr * 72 + seg * 16 + q * 4 + e] = f2bf(v[e]);
  }
  __syncthreads();
  short8 o0, o1;
#pragma unroll
  for (int e = 0; e < 8; ++e) o0[e] = (short)T[(seg * 16 + e) * 72 + rr];
#pragma unroll
  for (int e = 0; e < 8; ++e) o1[e] = (short)T[(seg * 16 + 8 + e) * 72 + rr];
  unsigned short* q2 = out + (size_t)(c0 + rr) * R + r0 + seg * 16;
  *(short8*)q2 = o0;
  *(short8*)(q2 + 8) = o1;
}

// ---------------- build V^T [B*H][64][2048] from qkv ----------------
__global__ __launch_bounds__(256) void k_build_vt(const unsigned short* __restrict__ qkv,
                                                  unsigned short* __restrict__ vt) {
  __shared__ unsigned short T[64 * 72];
  int n0 = blockIdx.x * 64;
  int bh = blockIdx.y;
  int b = bh >> 3, h = bh & 7;
  int t = threadIdx.x;
  int rr = t >> 2, seg = t & 3;
  const unsigned short* p =
      qkv + (size_t)(b * 2048 + n0 + rr) * 1536 + 1024 + h * 64 + seg * 16;
  *(short8*)&T[rr * 72 + seg * 16] = *(const short8*)p;
  *(short8*)&T[rr * 72 + seg * 16 + 8] = *(const short8*)(p + 8);
  __syncthreads();
  short8 o0, o1;
#pragma unroll
  for (int e = 0; e < 8; ++e) o0[e] = (short)T[(seg * 16 + e) * 72 + rr];
#pragma unroll
  for (int e = 0; e < 8; ++e) o1[e] = (short)T[(seg * 16 + 8 + e) * 72 + rr];
  unsigned short* q2 = vt + (size_t)(bh * 64 + rr) * 2048 + n0 + seg * 16;
  *(short8*)q2 = o0;
  *(short8*)(q2 + 8) = o1;
}

// ---------------- GEMM: C[M][N] = A[M][K] * Bt[N][K]^T (+bias) ----------------
// 128x128 tile, BK=64, 4 waves (each 64x64), global_load_lds staging.
template <bool F32OUT>
__global__ __launch_bounds__(256) void k_gemm_bt(
    const unsigned short* __restrict__ A, const unsigned short* __restrict__ Bt,
    void* __restrict__ Cp, const float* __restrict__ bias, int M, int N, int K) {
  __shared__ unsigned short Asm[128 * 64];
  __shared__ unsigned short Bsm[128 * 64];
  const int tid = threadIdx.x;
  const int lane = tid & 63, w = tid >> 6;
  const int wr = w >> 1, wc = w & 1;
  const int bm = blockIdx.y * 128, bn = blockIdx.x * 128;
  const int l15 = lane & 15, l4 = lane >> 4;
  f32x4 acc[4][4] = {};
  for (int k0 = 0; k0 < K; k0 += 64) {
    __syncthreads();
#pragma unroll
    for (int j = 0; j < 4; ++j) {
      int c = j * 256 + tid;
      gload16(A + (size_t)(bm + (c >> 3)) * K + k0 + ((c & 7) << 3),
              Asm + (size_t)(j * 256 + w * 64) * 8);
    }
#pragma unroll
    for (int j = 0; j < 4; ++j) {
      int c = j * 256 + tid;
      gload16(Bt + (size_t)(bn + (c >> 3)) * K + k0 + ((c & 7) << 3),
              Bsm + (size_t)(j * 256 + w * 64) * 8);
    }
    __syncthreads();
#pragma unroll
    for (int kc = 0; kc < 2; ++kc) {
      short8 av[4], bv[4];
#pragma unroll
      for (int i = 0; i < 4; ++i)
        av[i] = *(const short8*)&Asm[(wr * 64 + i * 16 + l15) * 64 + kc * 32 + l4 * 8];
#pragma unroll
      for (int j = 0; j < 4; ++j)
        bv[j] = *(const short8*)&Bsm[(wc * 64 + j * 16 + l15) * 64 + kc * 32 + l4 * 8];
#pragma unroll
      for (int i = 0; i < 4; ++i)
#pragma unroll
        for (int j = 0; j < 4; ++j)
          acc[i][j] = mfma16(av[i], bv[j], acc[i][j]);
    }
  }
#pragma unroll
  for (int i = 0; i < 4; ++i) {
#pragma unroll
    for (int j = 0; j < 4; ++j) {
      int col = bn + wc * 64 + j * 16 + l15;
      float bb = 0.f;
      if constexpr (F32OUT) bb = bias[col];
#pragma unroll
      for (int v = 0; v < 4; ++v) {
        int row = bm + wr * 64 + i * 16 + l4 * 4 + v;
        if constexpr (F32OUT) {
          ((float*)Cp)[(size_t)row * N + col] = acc[i][j][v] + bb;
        } else {
          ((unsigned short*)Cp)[(size_t)row * N + col] = f2bf(acc[i][j][v]);
        }
      }
    }
  }
}

// ---------------- flash attention ----------------
// grid (N/128, B*H), 512 threads = 8 waves, each wave owns 16 q-rows.
__global__ __launch_bounds__(512) void k_attn(const unsigned short* __restrict__ qkv,
                                              const unsigned short* __restrict__ vt,
                                              unsigned short* __restrict__ O) {
  __shared__ unsigned short Ksm[64 * 72];
  __shared__ unsigned short Vsm[64 * 72];
  __shared__ unsigned short Psm[8 * 16 * 72];
  const int tid = threadIdx.x;
  const int lane = tid & 63, w = tid >> 6;
  const int l15 = lane & 15, l4 = lane >> 4;
  const int q0 = blockIdx.x * 128;
  const int bh = blockIdx.y, b = bh >> 3, h = bh & 7;
  const float SCALE = 0.04419417382415922f;  // 512^-0.5

  short8 qf0, qf1;
  {
    const unsigned short* qp =
        qkv + (size_t)(b * 2048 + q0 + w * 16 + l15) * 1536 + h * 64 + l4 * 8;
    qf0 = *(const short8*)qp;
    qf1 = *(const short8*)(qp + 32);
  }
  f32x4 oacc[4] = {};
  float m_run[4] = {-INFINITY, -INFINITY, -INFINITY, -INFINITY};
  float l_run[4] = {0.f, 0.f, 0.f, 0.f};

  const int sr = tid >> 3, sc = (tid & 7) << 3;
  const unsigned short* kg = qkv + (size_t)b * 2048 * 1536 + 512 + h * 64 + sc;
  const unsigned short* vg = vt + (size_t)(bh * 64 + sr) * 2048 + sc;
  unsigned short* psm_w = Psm + w * 16 * 72;

  for (int kv0 = 0; kv0 < 2048; kv0 += 64) {
    __syncthreads();
    short8 kreg = *(const short8*)(kg + (size_t)(kv0 + sr) * 1536);
    short8 vreg = *(const short8*)(vg + kv0);
    *(short8*)&Ksm[sr * 72 + sc] = kreg;
    *(short8*)&Vsm[sr * 72 + sc] = vreg;
    __syncthreads();

    // S = Q K^T  (rows: q-local (l4*4+v), cols: kv-local (j*16+l15))
    f32x4 s[4];
#pragma unroll
    for (int j = 0; j < 4; ++j) {
      short8 kf0 = *(const short8*)&Ksm[(j * 16 + l15) * 72 + l4 * 8];
      short8 kf1 = *(const short8*)&Ksm[(j * 16 + l15) * 72 + 32 + l4 * 8];
      f32x4 z = {};
      z = mfma16(qf0, kf0, z);
      z = mfma16(qf1, kf1, z);
      s[j] = z;
    }
    // online softmax per row
#pragma unroll
    for (int v = 0; v < 4; ++v) {
      float s0 = s[0][v] * SCALE, s1 = s[1][v] * SCALE;
      float s2 = s[2][v] * SCALE, s3 = s[3][v] * SCALE;
      float rm = fmaxf(fmaxf(s0, s1), fmaxf(s2, s3));
      rm = fmaxf(rm, __shfl_xor(rm, 1));
      rm = fmaxf(rm, __shfl_xor(rm, 2));
      rm = fmaxf(rm, __shfl_xor(rm, 4));
      rm = fmaxf(rm, __shfl_xor(rm, 8));
      float mn = fmaxf(m_run[v], rm);
      float al = __expf(m_run[v] - mn);
      float p0 = __expf(s0 - mn), p1 = __expf(s1 - mn);
      float p2 = __expf(s2 - mn), p3 = __expf(s3 - mn);
      float rs = p0 + p1 + p2 + p3;
      rs += __shfl_xor(rs, 1);
      rs += __shfl_xor(rs, 2);
      rs += __shfl_xor(rs, 4);
      rs += __shfl_xor(rs, 8);
      m_run[v] = mn;
      l_run[v] = l_run[v] * al + rs;
      int pr = (l4 * 4 + v) * 72;
      psm_w[pr + l15] = f2bf(p0);
      psm_w[pr + 16 + l15] = f2bf(p1);
      psm_w[pr + 32 + l15] = f2bf(p2);
      psm_w[pr + 48 + l15] = f2bf(p3);
      oacc[0][v] *= al; oacc[1][v] *= al;
      oacc[2][v] *= al; oacc[3][v] *= al;
    }
    __syncthreads();
    // O += P V   (A = P rows l15, k = kv; B = Vt rows = d cols)
#pragma unroll
    for (int c = 0; c < 2; ++c) {
      short8 pf = *(const short8*)&psm_w[l15 * 72 + c * 32 + l4 * 8];
#pragma unroll
      for (int d = 0; d < 4; ++d) {
        short8 vf = *(const short8*)&Vsm[(d * 16 + l15) * 72 + c * 32 + l4 * 8];
        oacc[d] = mfma16(pf, vf, oacc[d]);
      }
    }
  }
#pragma unroll
  for (int v = 0; v < 4; ++v) {
    float inv = 1.0f / l_run[v];
    int n = q0 + w * 16 + l4 * 4 + v;
    unsigned short* op = O + (size_t)(b * 2048 + n) * 512 + h * 64 + l15;
#pragma unroll
    for (int d = 0; d < 4; ++d) op[d * 16] = f2bf(oacc[d][v] * inv);
  }
}

extern "C" void kernel_launch(void* const* d_in, const int* in_sizes, int n_in,
                              void* d_out, int out_size, void* d_ws, size_t ws_size,
                              hipStream_t stream) {
  const float* x = (const float*)d_in[0];
  const float* w_qkv = (const float*)d_in[1];
  const float* w_out = (const float*)d_in[2];
  const float* b_out = (const float*)d_in[3];
  float* out = (float*)d_out;
  char* ws = (char*)d_ws;

  unsigned short* xb    = (unsigned short*)(ws + 0);         //  8 MB [8192][512]
  unsigned short* wqkvT = (unsigned short*)(ws + 8388608);   //  1.5 MB [1536][512]
  unsigned short* woutT = (unsigned short*)(ws + 9961472);   //  0.5 MB [512][512]
  unsigned short* qkvb  = (unsigned short*)(ws + 10485760);  // 24 MB [8192][1536]
  unsigned short* vtb   = (unsigned short*)(ws + 35651584);  //  8 MB [32][64][2048]
  unsigned short* Ob    = (unsigned short*)(ws + 44040192);  //  8 MB [8192][512]

  k_convert<<<2048, 256, 0, stream>>>(x, xb);
  k_transpose_f32_bf16<<<dim3(24, 8), 256, 0, stream>>>(w_qkv, wqkvT, 512, 1536);
  k_transpose_f32_bf16<<<dim3(8, 8), 256, 0, stream>>>(w_out, woutT, 512, 512);
  k_gemm_bt<false><<<dim3(12, 64), 256, 0, stream>>>(xb, wqkvT, (void*)qkvb, nullptr,
                                                     8192, 1536, 512);
  k_build_vt<<<dim3(32, 32), 256, 0, stream>>>(qkvb, vtb);
  k_attn<<<dim3(16, 32), 512, 0, stream>>>(qkvb, vtb, Ob);
  k_gemm_bt<true><<<dim3(4, 64), 256, 0, stream>>>(Ob, woutT, (void*)out, b_out,
                                                   8192, 512, 512);
}

// Round 2
// 183.455 us; speedup vs baseline: 1.2886x; 1.2886x over previous
//
#include <hip/hip_runtime.h>

typedef __attribute__((ext_vector_type(4))) float f32x4;
typedef __attribute__((ext_vector_type(16))) float f32x16;
typedef __attribute__((ext_vector_type(8))) short short8;

#define DEV static __device__ __forceinline__

DEV unsigned short f2bf(float f) {
  union { float f; unsigned u; } x; x.f = f;
  unsigned r = x.u + 0x7fffu + ((x.u >> 16) & 1u);
  return (unsigned short)(r >> 16);
}

DEV float bf2f(unsigned short u) {
  union { unsigned u; float f; } x; x.u = ((unsigned)u) << 16;
  return x.f;
}

DEV f32x4 mfma16(short8 a, short8 b, f32x4 c) {
  return __builtin_amdgcn_mfma_f32_16x16x32_bf16(a, b, c, 0, 0, 0);
}

DEV f32x16 mfma32(short8 a, short8 b, f32x16 c) {
  return __builtin_amdgcn_mfma_f32_32x32x16_bf16(a, b, c, 0, 0, 0);
}

DEV void gload16(const void* g, void* l) {
  __builtin_amdgcn_global_load_lds(
      (const __attribute__((address_space(1))) void*)g,
      (__attribute__((address_space(3))) void*)l, 16, 0, 0);
}

DEV float exp2f_fast(float x) {
  float r;
  asm("v_exp_f32 %0, %1" : "=v"(r) : "v"(x));
  return r;
}

DEV unsigned cvtpk(float lo, float hi) {
  unsigned r;
  asm("v_cvt_pk_bf16_f32 %0, %1, %2" : "=v"(r) : "v"(lo), "v"(hi));
  return r;
}

DEV short8 mk8(unsigned w0, unsigned w1, unsigned w2, unsigned w3) {
  union { unsigned u[4]; short8 s; } x;
  x.u[0] = w0; x.u[1] = w1; x.u[2] = w2; x.u[3] = w3;
  return x.s;
}

// ---------------- fp32 -> bf16 elementwise ----------------
__global__ __launch_bounds__(256) void k_convert(const float* __restrict__ in,
                                                 unsigned short* __restrict__ out) {
  size_t i = (size_t)blockIdx.x * 256 + threadIdx.x;
  const f32x4* p = (const f32x4*)(in + i * 8);
  f32x4 a = p[0], b = p[1];
  short8 r;
  r[0] = f2bf(a[0]); r[1] = f2bf(a[1]); r[2] = f2bf(a[2]); r[3] = f2bf(a[3]);
  r[4] = f2bf(b[0]); r[5] = f2bf(b[1]); r[6] = f2bf(b[2]); r[7] = f2bf(b[3]);
  *(short8*)(out + i * 8) = r;
}

// ---------------- fp32 [R][C] -> bf16 [C][R] (weights) ----------------
__global__ __launch_bounds__(256) void k_transpose_f32_bf16(
    const float* __restrict__ in, unsigned short* __restrict__ out, int R, int C) {
  __shared__ unsigned short T[64 * 72];
  int r0 = blockIdx.y * 64, c0 = blockIdx.x * 64;
  int t = threadIdx.x;
  int rr = t >> 2, seg = t & 3;
  const float* p = in + (size_t)(r0 + rr) * C + c0 + seg * 16;
#pragma unroll
  for (int q = 0; q < 4; ++q) {
    f32x4 v = *(const f32x4*)(p + q * 4);
#pragma unroll
    for (int e = 0; e < 4; ++e) T[rr * 72 + seg * 16 + q * 4 + e] = f2bf(v[e]);
  }
  __syncthreads();
  short8 o0, o1;
#pragma unroll
  for (int e = 0; e < 8; ++e) o0[e] = (short)T[(seg * 16 + e) * 72 + rr];
#pragma unroll
  for (int e = 0; e < 8; ++e) o1[e] = (short)T[(seg * 16 + 8 + e) * 72 + rr];
  unsigned short* q2 = out + (size_t)(c0 + rr) * R + r0 + seg * 16;
  *(short8*)q2 = o0;
  *(short8*)(q2 + 8) = o1;
}

// ---------------- build V^T [B*H][64][2048] from qkv ----------------
__global__ __launch_bounds__(256) void k_build_vt(const unsigned short* __restrict__ qkv,
                                                  unsigned short* __restrict__ vt) {
  __shared__ unsigned short T[64 * 72];
  int n0 = blockIdx.x * 64;
  int bh = blockIdx.y;
  int b = bh >> 3, h = bh & 7;
  int t = threadIdx.x;
  int rr = t >> 2, seg = t & 3;
  const unsigned short* p =
      qkv + (size_t)(b * 2048 + n0 + rr) * 1536 + 1024 + h * 64 + seg * 16;
  *(short8*)&T[rr * 72 + seg * 16] = *(const short8*)p;
  *(short8*)&T[rr * 72 + seg * 16 + 8] = *(const short8*)(p + 8);
  __syncthreads();
  short8 o0, o1;
#pragma unroll
  for (int e = 0; e < 8; ++e) o0[e] = (short)T[(seg * 16 + e) * 72 + rr];
#pragma unroll
  for (int e = 0; e < 8; ++e) o1[e] = (short)T[(seg * 16 + 8 + e) * 72 + rr];
  unsigned short* q2 = vt + (size_t)(bh * 64 + rr) * 2048 + n0 + seg * 16;
  *(short8*)q2 = o0;
  *(short8*)(q2 + 8) = o1;
}

// ---------------- GEMM: C[M][N] = A[M][K] * Bt[N][K]^T (+bias) ----------------
template <bool F32OUT>
__global__ __launch_bounds__(256) void k_gemm_bt(
    const unsigned short* __restrict__ A, const unsigned short* __restrict__ Bt,
    void* __restrict__ Cp, const float* __restrict__ bias, int M, int N, int K) {
  __shared__ unsigned short Asm[128 * 64];
  __shared__ unsigned short Bsm[128 * 64];
  const int tid = threadIdx.x;
  const int lane = tid & 63, w = tid >> 6;
  const int wr = w >> 1, wc = w & 1;
  const int bm = blockIdx.y * 128, bn = blockIdx.x * 128;
  const int l15 = lane & 15, l4 = lane >> 4;
  f32x4 acc[4][4] = {};
  for (int k0 = 0; k0 < K; k0 += 64) {
    __syncthreads();
#pragma unroll
    for (int j = 0; j < 4; ++j) {
      int c = j * 256 + tid;
      gload16(A + (size_t)(bm + (c >> 3)) * K + k0 + ((c & 7) << 3),
              Asm + (size_t)(j * 256 + w * 64) * 8);
    }
#pragma unroll
    for (int j = 0; j < 4; ++j) {
      int c = j * 256 + tid;
      gload16(Bt + (size_t)(bn + (c >> 3)) * K + k0 + ((c & 7) << 3),
              Bsm + (size_t)(j * 256 + w * 64) * 8);
    }
    __syncthreads();
#pragma unroll
    for (int kc = 0; kc < 2; ++kc) {
      short8 av[4], bv[4];
#pragma unroll
      for (int i = 0; i < 4; ++i)
        av[i] = *(const short8*)&Asm[(wr * 64 + i * 16 + l15) * 64 + kc * 32 + l4 * 8];
#pragma unroll
      for (int j = 0; j < 4; ++j)
        bv[j] = *(const short8*)&Bsm[(wc * 64 + j * 16 + l15) * 64 + kc * 32 + l4 * 8];
#pragma unroll
      for (int i = 0; i < 4; ++i)
#pragma unroll
        for (int j = 0; j < 4; ++j)
          acc[i][j] = mfma16(av[i], bv[j], acc[i][j]);
    }
  }
#pragma unroll
  for (int i = 0; i < 4; ++i) {
#pragma unroll
    for (int j = 0; j < 4; ++j) {
      int col = bn + wc * 64 + j * 16 + l15;
      float bb = 0.f;
      if constexpr (F32OUT) bb = bias[col];
#pragma unroll
      for (int v = 0; v < 4; ++v) {
        int row = bm + wr * 64 + i * 16 + l4 * 4 + v;
        if constexpr (F32OUT) {
          ((float*)Cp)[(size_t)row * N + col] = acc[i][j][v] + bb;
        } else {
          ((unsigned short*)Cp)[(size_t)row * N + col] = f2bf(acc[i][j][v]);
        }
      }
    }
  }
}

// ---------------- flash attention, m214-style ----------------
// grid (N/128, B*H), 256 threads = 4 waves, each wave owns 32 q-rows.
// S^T = mfma32(K, Q): per lane col q = lane&31, rows kv = (r&3)+8*(r>>2)+4*hi.
// Softmax lane-local (+1 shfl_xor 32). P->bf16 A-frags via cvt_pk + half-swap.
// K/V staged in XOR-swizzled LDS, reg-prefetch double buffer, 1 barrier/tile.
__global__ __launch_bounds__(256, 2) void k_attn2(const unsigned short* __restrict__ qkv,
                                                  const unsigned short* __restrict__ vtg,
                                                  unsigned short* __restrict__ O) {
  __shared__ unsigned short Ksm[2][64 * 64];
  __shared__ unsigned short Vsm[2][64 * 64];
  __shared__ float sml[4][32];
  const int tid = threadIdx.x;
  const int lane = tid & 63, w = tid >> 6;
  const int l31 = lane & 31, hi = lane >> 5;
  const int bh = blockIdx.y, b = bh >> 3, h = bh & 7;
  const int q0 = blockIdx.x * 128 + w * 32;
  const float CL = 0.044194173824159216f * 1.4426950408889634f;  // SCALE*log2(e)

  // Q load, fold SCALE*log2e into bf16 Q
  short8 qf[4];
  {
    const unsigned short* qp = qkv + (size_t)(b * 2048 + q0 + l31) * 1536 + h * 64;
#pragma unroll
    for (int ks = 0; ks < 4; ++ks) {
      short8 raw = *(const short8*)(qp + ks * 16 + hi * 8);
      short8 f;
#pragma unroll
      for (int e = 0; e < 8; ++e)
        f[e] = (short)f2bf(bf2f((unsigned short)raw[e]) * CL);
      qf[ks] = f;
    }
  }

  // staging geometry: thread -> rows (sr, sr+32), 16B segment seg
  const int sr = tid >> 3, seg = tid & 7;
  const unsigned short* kg = qkv + (size_t)b * 2048 * 1536 + 512 + h * 64 + seg * 8;
  const unsigned short* vg = vtg + (size_t)bh * 64 * 2048 + seg * 8;
  const int wr1 = sr + 32;
  const int so0 = sr * 64 + ((seg * 8) ^ ((sr & 7) << 3));
  const int so1 = wr1 * 64 + ((seg * 8) ^ ((wr1 & 7) << 3));

  // prologue: stage tile 0 into buffer 0
  {
    short8 a = *(const short8*)(kg + (size_t)sr * 1536);
    short8 c = *(const short8*)(kg + (size_t)wr1 * 1536);
    short8 d0 = *(const short8*)(vg + (size_t)sr * 2048);
    short8 d1 = *(const short8*)(vg + (size_t)wr1 * 2048);
    *(short8*)&Ksm[0][so0] = a;  *(short8*)&Ksm[0][so1] = c;
    *(short8*)&Vsm[0][so0] = d0; *(short8*)&Vsm[0][so1] = d1;
  }
  __syncthreads();

  f32x16 oacc0 = {}, oacc1 = {};
  float m_run = 0.f, l_run = 0.f;
  const int rsw = (l31 & 7) << 3;  // read swizzle bits (shorts)

  for (int t = 0; t < 32; ++t) {
    const int cur = t & 1;
    const unsigned short* kb = Ksm[cur];
    const unsigned short* vb = Vsm[cur];

    // prefetch next K/V tile into regs (T14)
    short8 pk0, pk1, pv0, pv1;
    if (t < 31) {
      int kv = (t + 1) * 64;
      pk0 = *(const short8*)(kg + (size_t)(kv + sr) * 1536);
      pk1 = *(const short8*)(kg + (size_t)(kv + wr1) * 1536);
      pv0 = *(const short8*)(vg + (size_t)sr * 2048 + kv);
      pv1 = *(const short8*)(vg + (size_t)wr1 * 2048 + kv);
    }

    // S^T = K * Q^T  (two 32-kv subtiles, K=64 in 4 steps)
    f32x16 st[2] = {};
#pragma unroll
    for (int ks = 0; ks < 4; ++ks) {
      int col = ks * 16 + hi * 8;
      short8 kf0 = *(const short8*)&kb[l31 * 64 + (col ^ rsw)];
      short8 kf1 = *(const short8*)&kb[(32 + l31) * 64 + (col ^ rsw)];
      st[0] = mfma32(kf0, qf[ks], st[0]);
      st[1] = mfma32(kf1, qf[ks], st[1]);
    }

    // row max (tree), lane-local + cross-half combine
    float tm[8];
#pragma unroll
    for (int r = 0; r < 8; ++r)
      tm[r] = fmaxf(fmaxf(st[0][r], st[0][r + 8]), fmaxf(st[1][r], st[1][r + 8]));
    float pm = fmaxf(fmaxf(fmaxf(tm[0], tm[1]), fmaxf(tm[2], tm[3])),
                     fmaxf(fmaxf(tm[4], tm[5]), fmaxf(tm[6], tm[7])));
    pm = fmaxf(pm, __shfl_xor(pm, 32));

    // defer-max rescale (rare)
    if (!__all(pm <= m_run + 11.5f)) {
      float mn = fmaxf(m_run, pm);
      float al = exp2f_fast(m_run - mn);
      sml[w][l31] = al;
#pragma unroll
      for (int r = 0; r < 16; ++r) {
        float a = sml[w][(r & 3) + 8 * (r >> 2) + 4 * hi];
        oacc0[r] *= a;
        oacc1[r] *= a;
      }
      l_run *= al;
      m_run = mn;
    }

    // exp + pack P into A-fragments
    float lsum = 0.f;
    short8 pa[4];
#pragma unroll
    for (int s = 0; s < 2; ++s) {
      float p[16];
      float la = 0.f, lb = 0.f;
#pragma unroll
      for (int r = 0; r < 8; ++r) { p[r] = exp2f_fast(st[s][r] - m_run); la += p[r]; }
#pragma unroll
      for (int r = 8; r < 16; ++r) { p[r] = exp2f_fast(st[s][r] - m_run); lb += p[r]; }
      lsum += la + lb;
#pragma unroll
      for (int g = 0; g < 2; ++g) {
        unsigned pkA0 = cvtpk(p[8 * g + 0], p[8 * g + 1]);
        unsigned pkA1 = cvtpk(p[8 * g + 2], p[8 * g + 3]);
        unsigned pkB0 = cvtpk(p[8 * g + 4], p[8 * g + 5]);
        unsigned pkB1 = cvtpk(p[8 * g + 6], p[8 * g + 7]);
        unsigned tA0 = __shfl_xor(pkA0, 32), tA1 = __shfl_xor(pkA1, 32);
        unsigned tB0 = __shfl_xor(pkB0, 32), tB1 = __shfl_xor(pkB1, 32);
        unsigned w0 = hi ? tB0 : pkA0;
        unsigned w1 = hi ? tB1 : pkA1;
        unsigned w2 = hi ? pkB0 : tA0;
        unsigned w3 = hi ? pkB1 : tA1;
        pa[2 * s + g] = mk8(w0, w1, w2, w3);
      }
    }
    lsum += __shfl_xor(lsum, 32);
    l_run += lsum;

    // O += P V  (d-subtiles 0/1, kv in 4 steps of 16)
#pragma unroll
    for (int ks = 0; ks < 4; ++ks) {
      int col = ks * 16 + hi * 8;
      short8 vf0 = *(const short8*)&vb[l31 * 64 + (col ^ rsw)];
      short8 vf1 = *(const short8*)&vb[(32 + l31) * 64 + (col ^ rsw)];
      oacc0 = mfma32(pa[ks], vf0, oacc0);
      oacc1 = mfma32(pa[ks], vf1, oacc1);
    }

    // write prefetched tile into other buffer, single barrier per tile
    if (t < 31) {
      unsigned short* kn = Ksm[cur ^ 1];
      unsigned short* vn = Vsm[cur ^ 1];
      *(short8*)&kn[so0] = pk0; *(short8*)&kn[so1] = pk1;
      *(short8*)&vn[so0] = pv0; *(short8*)&vn[so1] = pv1;
    }
    __syncthreads();
  }

  // epilogue: divide by l (broadcast per-q l via LDS), write bf16 O
  sml[w][l31] = l_run;
#pragma unroll
  for (int r = 0; r < 16; ++r) {
    int qd = (r & 3) + 8 * (r >> 2) + 4 * hi;
    float linv = 1.0f / sml[w][qd];
    size_t row = (size_t)(b * 2048 + q0 + qd) * 512 + h * 64;
    O[row + l31] = f2bf(oacc0[r] * linv);
    O[row + 32 + l31] = f2bf(oacc1[r] * linv);
  }
}

extern "C" void kernel_launch(void* const* d_in, const int* in_sizes, int n_in,
                              void* d_out, int out_size, void* d_ws, size_t ws_size,
                              hipStream_t stream) {
  const float* x = (const float*)d_in[0];
  const float* w_qkv = (const float*)d_in[1];
  const float* w_out = (const float*)d_in[2];
  const float* b_out = (const float*)d_in[3];
  float* out = (float*)d_out;
  char* ws = (char*)d_ws;

  unsigned short* xb    = (unsigned short*)(ws + 0);         //  8 MB [8192][512]
  unsigned short* wqkvT = (unsigned short*)(ws + 8388608);   //  1.5 MB [1536][512]
  unsigned short* woutT = (unsigned short*)(ws + 9961472);   //  0.5 MB [512][512]
  unsigned short* qkvb  = (unsigned short*)(ws + 10485760);  // 24 MB [8192][1536]
  unsigned short* vtb   = (unsigned short*)(ws + 35651584);  //  8 MB [32][64][2048]
  unsigned short* Ob    = (unsigned short*)(ws + 44040192);  //  8 MB [8192][512]

  k_convert<<<2048, 256, 0, stream>>>(x, xb);
  k_transpose_f32_bf16<<<dim3(24, 8), 256, 0, stream>>>(w_qkv, wqkvT, 512, 1536);
  k_transpose_f32_bf16<<<dim3(8, 8), 256, 0, stream>>>(w_out, woutT, 512, 512);
  k_gemm_bt<false><<<dim3(12, 64), 256, 0, stream>>>(xb, wqkvT, (void*)qkvb, nullptr,
                                                     8192, 1536, 512);
  k_build_vt<<<dim3(32, 32), 256, 0, stream>>>(qkvb, vtb);
  k_attn2<<<dim3(16, 32), 256, 0, stream>>>(qkvb, vtb, Ob);
  k_gemm_bt<true><<<dim3(4, 64), 256, 0, stream>>>(Ob, woutT, (void*)out, b_out,
                                                   8192, 512, 512);
}